// Round 1
// 75.324 us; speedup vs baseline: 1.8633x; 1.8633x over previous
//
#include <hip/hip_runtime.h>

// Problem constants (match reference)
#define C_   64
#define H_   256
#define W_   256
#define L0_  1024   // j axis (g0 -> y taps)
#define L1_  1024   // i axis (g1 -> x taps)
#define JT   32     // j-tile per block

// Bicubic taps/weights, matches PyTorch grid_sample
// (bicubic, padding_mode='border', align_corners=True), A = -0.75.
__device__ __forceinline__ void cubic_prep(float g, int size, int idx[4], float w[4]) {
    const float A = -0.75f;
    float x  = (g + 1.0f) * 0.5f * (float)(size - 1);   // align_corners=True
    float x0 = floorf(x);
    float t  = x - x0;
    int   ix = (int)x0;
    float t2 = t * t, t3 = t2 * t;
    w[0] = A * (t3 - 2.0f * t2 + t);
    w[1] = (A + 2.0f) * t3 - (A + 3.0f) * t2 + 1.0f;
    float s = 1.0f - t, s2 = s * s;
    w[2] = (A + 2.0f) * s2 * s - (A + 3.0f) * s2 + 1.0f;
    float u = 2.0f - t, u2 = u * u;
    w[3] = A * u2 * u - 5.0f * A * u2 + 8.0f * A * u - 4.0f * A;
    idx[0] = min(max(ix - 1, 0), size - 1);   // border clamp
    idx[1] = min(max(ix,     0), size - 1);
    idx[2] = min(max(ix + 1, 0), size - 1);
    idx[3] = min(max(ix + 2, 0), size - 1);
}

// Y-FIRST separable bicubic. Block = (c, 32-j tile).
//   Tables : x-tap weights (float4) + pre-clamped packed x-tap indices, built
//            once per block into LDS (shared by all 1024 i).
//   Phase 1: y-interp. For each j in tile, combine 4 image ROWS (coalesced
//            256B loads) -> hy[x][j] in LDS, XOR-swizzled (j ^ (x&31)) so the
//            transpose write AND the phase-2 x-gather are both <=2-way (free).
//   Phase 2: per output, 4 conflict-free LDS gathers + 4 FMA; lanes span 32
//            consecutive j -> coalesced stores (2x128B per instr).
__global__ __launch_bounds__(256, 3) void bicubic_yfirst(const float* __restrict__ v,
                                                         const float* __restrict__ g0,
                                                         const float* __restrict__ g1,
                                                         float* __restrict__ out) {
    __shared__ float        hy[H_ * JT];   // 32 KB, hy[x*32 + (j ^ (x&31))]
    __shared__ float4       xw[L1_];       // 16 KB, x weights per i
    __shared__ unsigned int xip[L1_];      //  4 KB, packed clamped x-tap idx per i

    const int t  = threadIdx.x;
    const int c  = blockIdx.y;
    const int j0 = blockIdx.x * JT;

    // ---- build x-tap tables: 4 i's per thread (before the single barrier) ----
    {
        const int ib = t * 4;
#pragma unroll
        for (int s = 0; s < 4; ++s) {
            int i = ib + s;
            int xi4[4]; float w4[4];
            cubic_prep(g1[i], W_, xi4, w4);
            xw[i]  = make_float4(w4[0], w4[1], w4[2], w4[3]);
            xip[i] = (unsigned)xi4[0] | ((unsigned)xi4[1] << 8)
                   | ((unsigned)xi4[2] << 16) | ((unsigned)xi4[3] << 24);
        }
    }

    // ---- phase 1: y-interp rows -> hy (coalesced global reads) ----
    {
        const int x1 = t & 63;                 // lane -> x within row
        const int wv = t >> 6;                 // wave id: 8 j's per wave
        const float* vc = v + (size_t)c * (H_ * W_);
#pragma unroll
        for (int jj = 0; jj < JT / 4; ++jj) {
            int jl = wv * (JT / 4) + jj;       // uniform per wave
            int yi4[4]; float wy4[4];
            cubic_prep(g0[j0 + jl], H_, yi4, wy4);
            const float* r0 = vc + yi4[0] * W_;
            const float* r1 = vc + yi4[1] * W_;
            const float* r2 = vc + yi4[2] * W_;
            const float* r3 = vc + yi4[3] * W_;
#pragma unroll
            for (int k = 0; k < 4; ++k) {
                int x = x1 + 64 * k;
                float acc = wy4[0] * r0[x] + wy4[1] * r1[x]
                          + wy4[2] * r2[x] + wy4[3] * r3[x];
                hy[x * JT + (jl ^ (x & 31))] = acc;   // 2-way write, free
            }
        }
    }
    __syncthreads();

    // ---- phase 2: x-interp from LDS, coalesced stores ----
    {
        const int jl    = t & 31;              // lane -> j within tile
        const int ihalf = (t >> 5) & 1;        // two i's per wave-instr
        const int wv    = t >> 6;              // wave owns 256 consecutive i
        float* op = out + (size_t)c * ((size_t)L1_ * L0_)
                  + (size_t)(wv * 256 + ihalf) * L0_ + j0 + jl;
        int i = wv * 256 + ihalf;
#pragma unroll 4
        for (int it = 0; it < 128; ++it, i += 2, op += 2 * L0_) {
            unsigned p = xip[i];
            float4   w = xw[i];
            int xa = p & 255, xb = (p >> 8) & 255, xc = (p >> 16) & 255, xd = p >> 24;
            float o = w.x * hy[xa * JT + (jl ^ (xa & 31))]
                    + w.y * hy[xb * JT + (jl ^ (xb & 31))]
                    + w.z * hy[xc * JT + (jl ^ (xc & 31))]
                    + w.w * hy[xd * JT + (jl ^ (xd & 31))];
            *op = o;
        }
    }
}

extern "C" void kernel_launch(void* const* d_in, const int* in_sizes, int n_in,
                              void* d_out, int out_size, void* d_ws, size_t ws_size,
                              hipStream_t stream) {
    const float* values = (const float*)d_in[0];  // (1, C, H, W) fp32
    const float* g0     = (const float*)d_in[1];  // (L0,) fp32 -> y axis
    const float* g1     = (const float*)d_in[2];  // (L1,) fp32 -> x axis
    float* out          = (float*)d_out;          // (1, C, L1, L0) fp32

    dim3 grid(L0_ / JT, C_);   // (32, 64) = 2048 blocks
    bicubic_yfirst<<<grid, 256, 0, stream>>>(values, g0, g1, out);
}